// Round 6
// baseline (613.013 us; speedup 1.0000x reference)
//
#include <hip/hip_runtime.h>
#include <math.h>

#define NN 100000
#define NEDGE 1600000
#define NTOT 1700000          // edges + self loops
#define FIN 512
#define NH1 8
#define NC1 8
#define F1 64                 // NH1*NC1
#define NC2 10
#define SLOPE 0.2f
#define EPSF 1e-16f
#define SCAN_BLK 1024
#define NB ((NN + SCAN_BLK - 1) / SCAN_BLK)   // 98

typedef short short8 __attribute__((ext_vector_type(8)));
typedef float f32x4 __attribute__((ext_vector_type(4)));

__device__ __forceinline__ float lrelu(float x) { return x > 0.f ? x : SLOPE * x; }
__device__ __forceinline__ float eluf(float x) { return x > 0.f ? x : __expf(x) - 1.f; }

__device__ __forceinline__ unsigned short f2bf_rne(float f) {
    unsigned int u = __float_as_uint(f);
    unsigned int r = (u + 0x7FFFu + ((u >> 16) & 1u)) >> 16;
    return (unsigned short)r;
}
__device__ __forceinline__ float bf2f(unsigned short b) {
    return __uint_as_float(((unsigned int)b) << 16);
}

// ---------------- init: cnt=1 (self-loop) + W1^T bf16 ----------------
__global__ void k_init(const float* __restrict__ W, unsigned short* __restrict__ wT,
                       int* __restrict__ cnt)
{
    int i = blockIdx.x * 256 + threadIdx.x;
    if (i < NN) cnt[i] = 1;
    if (i < F1 * FIN) {
        int n = i & 63, k = i >> 6;
        wT[n * FIN + k] = f2bf_rne(W[k * F1 + n]);
    }
}

// ---------------- GEMM1 (MFMA bf16) + fused al/ar epilogue ----------------
#define LDA 40    // bf16 row stride (80 B)

__global__ __launch_bounds__(256) void k_gemm1(const float* __restrict__ x,
                                               const unsigned short* __restrict__ wT,
                                               const float* __restrict__ asrc,
                                               const float* __restrict__ adst,
                                               unsigned short* __restrict__ h1b,
                                               float* __restrict__ al,
                                               float* __restrict__ ar)
{
    __shared__ unsigned short Al[64][LDA];
    __shared__ unsigned short Bl[64][LDA];
    __shared__ float sas[F1], sad[F1];
    const int tid = threadIdx.x;
    const int row0 = blockIdx.x * 64;
    const int w  = tid >> 6;
    const int l  = tid & 63;
    const int lr = l & 15;
    const int lg = l >> 4;
    if (tid < F1) { sas[tid] = asrc[tid]; sad[tid] = adst[tid]; }
    f32x4 acc[4] = {};

    for (int k0 = 0; k0 < FIN; k0 += 32) {
        #pragma unroll
        for (int t2 = 0; t2 < 2; ++t2) {
            int idx = tid + t2 * 256;
            int r = idx >> 3, q = idx & 7;
            int gr = row0 + r;
            float4 v = (gr < NN) ? *(const float4*)(x + (size_t)gr * FIN + k0 + 4 * q)
                                 : make_float4(0.f, 0.f, 0.f, 0.f);
            ushort4 u;
            u.x = f2bf_rne(v.x); u.y = f2bf_rne(v.y);
            u.z = f2bf_rne(v.z); u.w = f2bf_rne(v.w);
            *(ushort4*)&Al[r][4 * q] = u;
        }
        {
            int n = tid >> 2, q = tid & 3;
            *(uint4*)&Bl[n][8 * q] = *(const uint4*)(wT + (size_t)n * FIN + k0 + 8 * q);
        }
        __syncthreads();
        short8 a = *(const short8*)&Al[16 * w + lr][8 * lg];
        #pragma unroll
        for (int nt = 0; nt < 4; ++nt) {
            short8 b = *(const short8*)&Bl[16 * nt + lr][8 * lg];
            acc[nt] = __builtin_amdgcn_mfma_f32_16x16x32_bf16(a, b, acc[nt], 0, 0, 0);
        }
        __syncthreads();
    }
    // h1b write: D lane mapping col=lr, row=4*lg+reg
    #pragma unroll
    for (int r = 0; r < 4; ++r) {
        int gr = row0 + 16 * w + 4 * lg + r;
        if (gr < NN) {
            #pragma unroll
            for (int nt = 0; nt < 4; ++nt)
                h1b[(size_t)gr * F1 + 16 * nt + lr] = f2bf_rne(acc[nt][r]);
        }
    }
    // fused al/ar: head = 2*nt + (lr>>3); reduce over the 8 lanes of lr&7
    float pa[4][4], pd[4][4];
    #pragma unroll
    for (int nt = 0; nt < 4; ++nt) {
        float wa = sas[16 * nt + lr], wd = sad[16 * nt + lr];
        #pragma unroll
        for (int r = 0; r < 4; ++r) {
            float c = acc[nt][r];
            pa[nt][r] = c * wa;
            pd[nt][r] = c * wd;
        }
    }
    #pragma unroll
    for (int d = 1; d <= 4; d <<= 1) {
        #pragma unroll
        for (int nt = 0; nt < 4; ++nt)
            #pragma unroll
            for (int r = 0; r < 4; ++r) {
                pa[nt][r] += __shfl_xor(pa[nt][r], d);
                pd[nt][r] += __shfl_xor(pd[nt][r], d);
            }
    }
    int low3 = lr & 7, hi = lr >> 3;
    if (low3 < 4) {
        int head = 2 * low3 + hi;
        #pragma unroll
        for (int nt = 0; nt < 4; ++nt) {
            if (low3 == nt) {
                #pragma unroll
                for (int r = 0; r < 4; ++r) {
                    int gr = row0 + 16 * w + 4 * lg + r;
                    if (gr < NN) {
                        al[gr * NH1 + head] = pa[nt][r];
                        ar[gr * NH1 + head] = pd[nt][r];
                    }
                }
            }
        }
    }
}

// ---------------- CSR build ----------------
__global__ void k_hist(const int* __restrict__ ei, int* __restrict__ cnt,
                       int* __restrict__ pos)
{
    int e = blockIdx.x * blockDim.x + threadIdx.x;
    if (e >= NEDGE) return;
    pos[e] = atomicAdd(&cnt[ei[NEDGE + e]], 1);   // >=1 (slot 0 = self-loop)
}

__global__ __launch_bounds__(256) void k_scan1(const int* __restrict__ cnt,
                                               int* __restrict__ off,
                                               int* __restrict__ bsum)
{
    __shared__ int s[256];
    int t = threadIdx.x;
    int base = blockIdx.x * SCAN_BLK + t * 4;
    int c0 = (base + 0 < NN) ? cnt[base + 0] : 0;
    int c1 = (base + 1 < NN) ? cnt[base + 1] : 0;
    int c2 = (base + 2 < NN) ? cnt[base + 2] : 0;
    int c3 = (base + 3 < NN) ? cnt[base + 3] : 0;
    int ts = c0 + c1 + c2 + c3;
    s[t] = ts;
    __syncthreads();
    #pragma unroll
    for (int d = 1; d < 256; d <<= 1) {
        int v = (t >= d) ? s[t - d] : 0;
        __syncthreads();
        s[t] += v;
        __syncthreads();
    }
    int run = s[t] - ts;
    if (t == 255) bsum[blockIdx.x] = s[255];
    if (base + 0 < NN) off[base + 0] = run; run += c0;
    if (base + 1 < NN) off[base + 1] = run; run += c1;
    if (base + 2 < NN) off[base + 2] = run; run += c2;
    if (base + 3 < NN) off[base + 3] = run;
}

__global__ void k_scan2(int* __restrict__ bsum, int* __restrict__ off)
{
    __shared__ int s[128];
    int t = threadIdx.x;
    int v = (t < NB) ? bsum[t] : 0;
    s[t] = v;
    __syncthreads();
    #pragma unroll
    for (int d = 1; d < 128; d <<= 1) {
        int w = (t >= d) ? s[t - d] : 0;
        __syncthreads();
        s[t] += w;
        __syncthreads();
    }
    if (t < NB) bsum[t] = s[t] - v;
    if (t == 0) off[NN] = NTOT;
}

__global__ void k_scan3(int* __restrict__ off, const int* __restrict__ bsum,
                        int* __restrict__ esrc)
{
    int i = blockIdx.x * blockDim.x + threadIdx.x;
    if (i >= NN) return;
    int o = off[i] + bsum[i >> 10];
    off[i] = o;
    esrc[o] = i;          // self-loop in slot 0
}

__global__ void k_scatter(const int* __restrict__ ei, const int* __restrict__ off,
                          const int* __restrict__ pos, int* __restrict__ esrc)
{
    int e = blockIdx.x * blockDim.x + threadIdx.x;
    if (e >= NEDGE) return;
    esrc[off[ei[NEDGE + e]] + pos[e]] = ei[e];
}

// ------- agg1: wave per node, 4 edge-slots x 16 lanes; fused l2prep -------
// lane = 16*sub + li; lane owns channels 4*li..4*li+3 of edge-slot sub; head = li>>1
__global__ __launch_bounds__(256) void k_agg1(const int* __restrict__ off,
                                              const int* __restrict__ esrc,
                                              const float* __restrict__ al,
                                              const float* __restrict__ ar,
                                              const unsigned short* __restrict__ h1b,
                                              const float* __restrict__ b1,
                                              const float* __restrict__ W2,
                                              const float* __restrict__ as2,
                                              const float* __restrict__ ad2,
                                              float* __restrict__ packed)
{
    __shared__ float sW[F1 * NC2];
    __shared__ float sb1[F1];
    __shared__ float s2a[NC2], s2d[NC2];
    int tid = threadIdx.x;
    for (int i = tid; i < F1 * NC2; i += 256) sW[i] = W2[i];
    if (tid < F1) sb1[tid] = b1[tid];
    if (tid < NC2) { s2a[tid] = as2[tid]; s2d[tid] = ad2[tid]; }
    __syncthreads();

    int node = blockIdx.x * 4 + (tid >> 6);
    int lane = tid & 63;
    int sub  = lane >> 4;       // edge slot 0..3
    int li   = lane & 15;       // channel group
    int head = li >> 1;
    int beg = off[node], end = off[node + 1];
    float arn = ar[node * NH1 + head];

    float a0 = 0.f, a1 = 0.f, a2 = 0.f, a3 = 0.f, ds = 0.f;
    for (int i = beg + sub; i < end; i += 4) {
        int s = esrc[i];
        float e = __expf(lrelu(al[s * NH1 + head] + arn));
        ushort4 hv = *(const ushort4*)(h1b + (size_t)s * F1 + 4 * li);
        a0 += bf2f(hv.x) * e;
        a1 += bf2f(hv.y) * e;
        a2 += bf2f(hv.z) * e;
        a3 += bf2f(hv.w) * e;
        ds += e;
    }
    // combine the 4 edge slots (xor across sub bits only)
    #pragma unroll
    for (int d = 16; d <= 32; d <<= 1) {
        a0 += __shfl_xor(a0, d);
        a1 += __shfl_xor(a1, d);
        a2 += __shfl_xor(a2, d);
        a3 += __shfl_xor(a3, d);
        ds += __shfl_xor(ds, d);
    }
    float inv = 1.f / (ds + EPSF);
    float g0 = eluf(a0 * inv + sb1[4 * li + 0]);
    float g1 = eluf(a1 * inv + sb1[4 * li + 1]);
    float g2 = eluf(a2 * inv + sb1[4 * li + 2]);
    float g3 = eluf(a3 * inv + sb1[4 * li + 3]);

    // h2 = g @ W2 : per-lane partial over its 4 channels, xor-reduce over li bits
    float p[NC2];
    #pragma unroll
    for (int o = 0; o < NC2; ++o)
        p[o] = g0 * sW[(4 * li + 0) * NC2 + o] + g1 * sW[(4 * li + 1) * NC2 + o]
             + g2 * sW[(4 * li + 2) * NC2 + o] + g3 * sW[(4 * li + 3) * NC2 + o];
    #pragma unroll
    for (int d = 1; d <= 8; d <<= 1)
        #pragma unroll
        for (int o = 0; o < NC2; ++o) p[o] += __shfl_xor(p[o], d);

    float sa = 0.f, sd = 0.f;
    #pragma unroll
    for (int o = 0; o < NC2; ++o) { sa += p[o] * s2a[o]; sd += p[o] * s2d[o]; }

    float* rec = packed + (size_t)node * 16;       // 64B-aligned record
    if (lane < NC2) rec[lane] = p[lane];
    if (lane == 10) rec[10] = sa;
    if (lane == 11) rec[11] = sd;
}

// ------- agg2: wave per node, 4 edge-slots x 16 lanes; fused log_softmax -------
__global__ __launch_bounds__(256) void k_agg2(const int* __restrict__ off,
                                              const int* __restrict__ esrc,
                                              const float* __restrict__ packed,
                                              const float* __restrict__ b2,
                                              float* __restrict__ out)
{
    int tid = threadIdx.x;
    int node = blockIdx.x * 4 + (tid >> 6);
    int lane = tid & 63;
    int sub  = lane >> 4;
    int li   = lane & 15;
    int beg = off[node], end = off[node + 1];
    float arn = packed[(size_t)node * 16 + 11];

    float acc = 0.f, ds = 0.f;
    for (int i = beg + sub; i < end; i += 4) {
        int s = esrc[i];
        float v = (li < 12) ? packed[(size_t)s * 16 + li] : 0.f;
        float al2s = __shfl(v, 10, 16);
        float e = __expf(lrelu(al2s + arn));
        if (li < NC2) acc += v * e;
        ds += e;
    }
    #pragma unroll
    for (int d = 16; d <= 32; d <<= 1) {
        acc += __shfl_xor(acc, d);
        ds  += __shfl_xor(ds, d);
    }
    float z = (li < NC2) ? acc / (ds + EPSF) + b2[li] : -1e30f;
    float m = z;
    #pragma unroll
    for (int d = 8; d >= 1; d >>= 1) m = fmaxf(m, __shfl_xor(m, d, 16));
    float ex = (li < NC2) ? __expf(z - m) : 0.f;
    float ss = ex;
    #pragma unroll
    for (int d = 8; d >= 1; d >>= 1) ss += __shfl_xor(ss, d, 16);
    float ls = __logf(ss) + m;
    if (lane < NC2) out[(size_t)node * NC2 + lane] = z - ls;   // group 0 writes
}

extern "C" void kernel_launch(void* const* d_in, const int* in_sizes, int n_in,
                              void* d_out, int out_size, void* d_ws, size_t ws_size,
                              hipStream_t stream)
{
    const float* x    = (const float*)d_in[0];
    const int*   ei   = (const int*)d_in[1];
    const float* W1   = (const float*)d_in[2];
    const float* as1  = (const float*)d_in[3];
    const float* ad1  = (const float*)d_in[4];
    const float* b1   = (const float*)d_in[5];
    const float* W2   = (const float*)d_in[6];
    const float* as2  = (const float*)d_in[7];
    const float* ad2  = (const float*)d_in[8];
    const float* b2   = (const float*)d_in[9];
    float* out = (float*)d_out;

    char* ws = (char*)d_ws;
    unsigned short* h1b = (unsigned short*)ws;                     // NN*64 bf16
    unsigned short* wT  = h1b + (size_t)NN * F1;                   // 64*512 bf16
    float* al1 = (float*)(wT + (size_t)F1 * FIN);                  // NN*8
    float* ar1 = al1 + (size_t)NN * NH1;                           // NN*8
    float* packed = ar1 + (size_t)NN * NH1;                        // NN*16 (64B recs)
    int* cnt   = (int*)(packed + (size_t)NN * 16);                 // NN
    int* off   = cnt + NN;                                         // NN+1
    int* bsum  = off + NN + 1;                                     // 128
    int* esrc  = bsum + 128;                                       // NTOT
    int* pos   = esrc + NTOT;                                      // NEDGE

    k_init<<<(NN + 255) / 256, 256, 0, stream>>>(W1, wT, cnt);
    k_gemm1<<<(NN + 63) / 64, 256, 0, stream>>>(x, wT, as1, ad1, h1b, al1, ar1);
    k_hist<<<(NEDGE + 255) / 256, 256, 0, stream>>>(ei, cnt, pos);
    k_scan1<<<NB, 256, 0, stream>>>(cnt, off, bsum);
    k_scan2<<<1, 128, 0, stream>>>(bsum, off);
    k_scan3<<<(NN + 255) / 256, 256, 0, stream>>>(off, bsum, esrc);
    k_scatter<<<(NEDGE + 255) / 256, 256, 0, stream>>>(ei, off, pos, esrc);
    k_agg1<<<NN / 4, 256, 0, stream>>>(off, esrc, al1, ar1, h1b, b1, W2, as2, ad2, packed);
    k_agg2<<<NN / 4, 256, 0, stream>>>(off, esrc, packed, b2, out);
}

// Round 8
// 607.948 us; speedup vs baseline: 1.0083x; 1.0083x over previous
//
#include <hip/hip_runtime.h>
#include <math.h>

#define NN 100000
#define NEDGE 1600000
#define NTOT 1700000          // edges + self loops
#define FIN 512
#define NH1 8
#define NC1 8
#define F1 64                 // NH1*NC1
#define NC2 10
#define SLOPE 0.2f
#define EPSF 1e-16f
#define SCAN_BLK 1024
#define NB ((NN + SCAN_BLK - 1) / SCAN_BLK)   // 98

typedef short short8 __attribute__((ext_vector_type(8)));
typedef float f32x4 __attribute__((ext_vector_type(4)));

__device__ __forceinline__ float lrelu(float x) { return x > 0.f ? x : SLOPE * x; }
__device__ __forceinline__ float eluf(float x) { return x > 0.f ? x : __expf(x) - 1.f; }

__device__ __forceinline__ unsigned short f2bf_rne(float f) {
    unsigned int u = __float_as_uint(f);
    unsigned int r = (u + 0x7FFFu + ((u >> 16) & 1u)) >> 16;
    return (unsigned short)r;
}
__device__ __forceinline__ float bf2f(unsigned short b) {
    return __uint_as_float(((unsigned int)b) << 16);
}

// ---- fp8 e4m3fn codec via exponent-shift trick (subnormals handled naturally) ----
__device__ __forceinline__ unsigned char f2fp8(float f) {
    unsigned int u = __float_as_uint(f * 7.523163845262640e-37f);   // * 2^-120
    unsigned int s = (u >> 24) & 0x80u;
    unsigned int mag = u & 0x7FFFFFFFu;
    unsigned int r = (mag + 0x7FFFFu + ((mag >> 20) & 1u)) >> 20;   // RNE to 3-bit mantissa
    if (r > 0x7Eu) r = 0x7Eu;                                       // clamp (avoid NaN 0x7F)
    return (unsigned char)(s | r);
}
__device__ __forceinline__ float fp82f(unsigned int b) {
    unsigned int s = (b & 0x80u) << 24;
    unsigned int mag = (b & 0x7Fu) << 20;
    return __uint_as_float(s | mag) * 1.329227995784916e+36f;       // * 2^120
}

// ---------------- init: cnt=1 (self-loop) + W1^T bf16 ----------------
__global__ void k_init(const float* __restrict__ W, unsigned short* __restrict__ wT,
                       int* __restrict__ cnt)
{
    int i = blockIdx.x * 256 + threadIdx.x;
    if (i < NN) cnt[i] = 1;
    if (i < F1 * FIN) {
        int n = i & 63, k = i >> 6;
        wT[n * FIN + k] = f2bf_rne(W[k * F1 + n]);
    }
}

// ---------------- GEMM1 (MFMA bf16) + fused al/ar epilogue; h1 stored fp8 ----------------
#define LDA 40    // bf16 row stride (80 B)

__global__ __launch_bounds__(256) void k_gemm1(const float* __restrict__ x,
                                               const unsigned short* __restrict__ wT,
                                               const float* __restrict__ asrc,
                                               const float* __restrict__ adst,
                                               unsigned char* __restrict__ h1f8,
                                               unsigned short* __restrict__ al1b,
                                               float* __restrict__ ar)
{
    __shared__ unsigned short Al[64][LDA];
    __shared__ unsigned short Bl[64][LDA];
    __shared__ float sas[F1], sad[F1];
    const int tid = threadIdx.x;
    const int row0 = blockIdx.x * 64;
    const int w  = tid >> 6;
    const int l  = tid & 63;
    const int lr = l & 15;
    const int lg = l >> 4;
    if (tid < F1) { sas[tid] = asrc[tid]; sad[tid] = adst[tid]; }
    f32x4 acc[4] = {};

    for (int k0 = 0; k0 < FIN; k0 += 32) {
        #pragma unroll
        for (int t2 = 0; t2 < 2; ++t2) {
            int idx = tid + t2 * 256;
            int r = idx >> 3, q = idx & 7;
            int gr = row0 + r;
            float4 v = (gr < NN) ? *(const float4*)(x + (size_t)gr * FIN + k0 + 4 * q)
                                 : make_float4(0.f, 0.f, 0.f, 0.f);
            ushort4 u;
            u.x = f2bf_rne(v.x); u.y = f2bf_rne(v.y);
            u.z = f2bf_rne(v.z); u.w = f2bf_rne(v.w);
            *(ushort4*)&Al[r][4 * q] = u;
        }
        {
            int n = tid >> 2, q = tid & 3;
            *(uint4*)&Bl[n][8 * q] = *(const uint4*)(wT + (size_t)n * FIN + k0 + 8 * q);
        }
        __syncthreads();
        short8 a = *(const short8*)&Al[16 * w + lr][8 * lg];
        #pragma unroll
        for (int nt = 0; nt < 4; ++nt) {
            short8 b = *(const short8*)&Bl[16 * nt + lr][8 * lg];
            acc[nt] = __builtin_amdgcn_mfma_f32_16x16x32_bf16(a, b, acc[nt], 0, 0, 0);
        }
        __syncthreads();
    }
    // h1 write (fp8): D lane mapping col=lr, row=4*lg+reg
    #pragma unroll
    for (int r = 0; r < 4; ++r) {
        int gr = row0 + 16 * w + 4 * lg + r;
        if (gr < NN) {
            #pragma unroll
            for (int nt = 0; nt < 4; ++nt)
                h1f8[(size_t)gr * F1 + 16 * nt + lr] = f2fp8(acc[nt][r]);
        }
    }
    // fused al/ar: head = 2*nt + (lr>>3); reduce over the 8 lanes of lr&7
    float pa[4][4], pd[4][4];
    #pragma unroll
    for (int nt = 0; nt < 4; ++nt) {
        float wa = sas[16 * nt + lr], wd = sad[16 * nt + lr];
        #pragma unroll
        for (int r = 0; r < 4; ++r) {
            float c = acc[nt][r];
            pa[nt][r] = c * wa;
            pd[nt][r] = c * wd;
        }
    }
    #pragma unroll
    for (int d = 1; d <= 4; d <<= 1) {
        #pragma unroll
        for (int nt = 0; nt < 4; ++nt)
            #pragma unroll
            for (int r = 0; r < 4; ++r) {
                pa[nt][r] += __shfl_xor(pa[nt][r], d);
                pd[nt][r] += __shfl_xor(pd[nt][r], d);
            }
    }
    int low3 = lr & 7, hi = lr >> 3;
    if (low3 < 4) {
        int head = 2 * low3 + hi;
        #pragma unroll
        for (int nt = 0; nt < 4; ++nt) {
            if (low3 == nt) {
                #pragma unroll
                for (int r = 0; r < 4; ++r) {
                    int gr = row0 + 16 * w + 4 * lg + r;
                    if (gr < NN) {
                        al1b[gr * NH1 + head] = f2bf_rne(pa[nt][r]);
                        ar[gr * NH1 + head] = pd[nt][r];
                    }
                }
            }
        }
    }
}

// ---------------- CSR build ----------------
__global__ void k_hist(const int* __restrict__ ei, int* __restrict__ cnt,
                       int* __restrict__ pos)
{
    int e = blockIdx.x * blockDim.x + threadIdx.x;
    if (e >= NEDGE) return;
    pos[e] = atomicAdd(&cnt[ei[NEDGE + e]], 1);   // >=1 (slot 0 = self-loop)
}

__global__ __launch_bounds__(256) void k_scan1(const int* __restrict__ cnt,
                                               int* __restrict__ off,
                                               int* __restrict__ bsum)
{
    __shared__ int s[256];
    int t = threadIdx.x;
    int base = blockIdx.x * SCAN_BLK + t * 4;
    int c0 = (base + 0 < NN) ? cnt[base + 0] : 0;
    int c1 = (base + 1 < NN) ? cnt[base + 1] : 0;
    int c2 = (base + 2 < NN) ? cnt[base + 2] : 0;
    int c3 = (base + 3 < NN) ? cnt[base + 3] : 0;
    int ts = c0 + c1 + c2 + c3;
    s[t] = ts;
    __syncthreads();
    #pragma unroll
    for (int d = 1; d < 256; d <<= 1) {
        int v = (t >= d) ? s[t - d] : 0;
        __syncthreads();
        s[t] += v;
        __syncthreads();
    }
    int run = s[t] - ts;
    if (t == 255) bsum[blockIdx.x] = s[255];
    if (base + 0 < NN) off[base + 0] = run; run += c0;
    if (base + 1 < NN) off[base + 1] = run; run += c1;
    if (base + 2 < NN) off[base + 2] = run; run += c2;
    if (base + 3 < NN) off[base + 3] = run;
}

__global__ void k_scan2(int* __restrict__ bsum, int* __restrict__ off)
{
    __shared__ int s[128];
    int t = threadIdx.x;
    int v = (t < NB) ? bsum[t] : 0;
    s[t] = v;
    __syncthreads();
    #pragma unroll
    for (int d = 1; d < 128; d <<= 1) {
        int w = (t >= d) ? s[t - d] : 0;
        __syncthreads();
        s[t] += w;
        __syncthreads();
    }
    if (t < NB) bsum[t] = s[t] - v;
    if (t == 0) off[NN] = NTOT;
}

__global__ void k_scan3(int* __restrict__ off, const int* __restrict__ bsum,
                        int* __restrict__ esrc)
{
    int i = blockIdx.x * blockDim.x + threadIdx.x;
    if (i >= NN) return;
    int o = off[i] + bsum[i >> 10];
    off[i] = o;
    esrc[o] = i;          // self-loop in slot 0
}

__global__ void k_scatter(const int* __restrict__ ei, const int* __restrict__ off,
                          const int* __restrict__ pos, int* __restrict__ esrc)
{
    int e = blockIdx.x * blockDim.x + threadIdx.x;
    if (e >= NEDGE) return;
    esrc[off[ei[NEDGE + e]] + pos[e]] = ei[e];
}

// ------- agg1: wave per node, 4 edge-slots x 16 lanes; fp8 h gather; fused l2prep -------
// lane = 16*sub + li; lane owns channels 4*li..4*li+3 of edge-slot sub; head = li>>1
__global__ __launch_bounds__(256) void k_agg1(const int* __restrict__ off,
                                              const int* __restrict__ esrc,
                                              const unsigned short* __restrict__ al1b,
                                              const float* __restrict__ ar,
                                              const unsigned char* __restrict__ h1f8,
                                              const float* __restrict__ b1,
                                              const float* __restrict__ W2,
                                              const float* __restrict__ as2,
                                              const float* __restrict__ ad2,
                                              unsigned short* __restrict__ packedb)
{
    __shared__ float sW[F1 * NC2];
    __shared__ float sb1[F1];
    __shared__ float s2a[NC2], s2d[NC2];
    int tid = threadIdx.x;
    for (int i = tid; i < F1 * NC2; i += 256) sW[i] = W2[i];
    if (tid < F1) sb1[tid] = b1[tid];
    if (tid < NC2) { s2a[tid] = as2[tid]; s2d[tid] = ad2[tid]; }
    __syncthreads();

    int node = blockIdx.x * 4 + (tid >> 6);
    int lane = tid & 63;
    int sub  = lane >> 4;       // edge slot 0..3
    int li   = lane & 15;       // channel group
    int head = li >> 1;
    int beg = off[node], end = off[node + 1];
    float arn = ar[node * NH1 + head];

    float a0 = 0.f, a1 = 0.f, a2 = 0.f, a3 = 0.f, ds = 0.f;
    for (int i = beg + sub; i < end; i += 4) {
        int s = esrc[i];
        float e = __expf(lrelu(bf2f(al1b[s * NH1 + head]) + arn));
        unsigned int w = *(const unsigned int*)(h1f8 + (size_t)s * F1 + 4 * li);
        a0 += fp82f(w & 0xFFu) * e;
        a1 += fp82f((w >> 8) & 0xFFu) * e;
        a2 += fp82f((w >> 16) & 0xFFu) * e;
        a3 += fp82f(w >> 24) * e;
        ds += e;
    }
    // combine the 4 edge slots (xor across sub bits only)
    #pragma unroll
    for (int d = 16; d <= 32; d <<= 1) {
        a0 += __shfl_xor(a0, d);
        a1 += __shfl_xor(a1, d);
        a2 += __shfl_xor(a2, d);
        a3 += __shfl_xor(a3, d);
        ds += __shfl_xor(ds, d);
    }
    float inv = 1.f / (ds + EPSF);
    float g0 = eluf(a0 * inv + sb1[4 * li + 0]);
    float g1 = eluf(a1 * inv + sb1[4 * li + 1]);
    float g2 = eluf(a2 * inv + sb1[4 * li + 2]);
    float g3 = eluf(a3 * inv + sb1[4 * li + 3]);

    // h2 = g @ W2 : per-lane partial over its 4 channels, xor-reduce over li bits
    float p[NC2];
    #pragma unroll
    for (int o = 0; o < NC2; ++o)
        p[o] = g0 * sW[(4 * li + 0) * NC2 + o] + g1 * sW[(4 * li + 1) * NC2 + o]
             + g2 * sW[(4 * li + 2) * NC2 + o] + g3 * sW[(4 * li + 3) * NC2 + o];
    #pragma unroll
    for (int d = 1; d <= 8; d <<= 1)
        #pragma unroll
        for (int o = 0; o < NC2; ++o) p[o] += __shfl_xor(p[o], d);

    float sa = 0.f, sd = 0.f;
    #pragma unroll
    for (int o = 0; o < NC2; ++o) { sa += p[o] * s2a[o]; sd += p[o] * s2d[o]; }

    // 32B record: [0..9]=h2 bf16, [10]=al2 bf16, [11]=ar2 bf16
    unsigned short* rec = packedb + (size_t)node * 16;
    if (lane < NC2) rec[lane] = f2bf_rne(p[lane]);
    if (lane == 10) rec[10] = f2bf_rne(sa);
    if (lane == 11) rec[11] = f2bf_rne(sd);
}

// ------- agg2: wave per node, 4 edge-slots x 16 lanes; 32B records; fused log_softmax -------
__global__ __launch_bounds__(256) void k_agg2(const int* __restrict__ off,
                                              const int* __restrict__ esrc,
                                              const unsigned short* __restrict__ packedb,
                                              const float* __restrict__ b2,
                                              float* __restrict__ out)
{
    int tid = threadIdx.x;
    int node = blockIdx.x * 4 + (tid >> 6);
    int lane = tid & 63;
    int sub  = lane >> 4;
    int li   = lane & 15;
    int beg = off[node], end = off[node + 1];
    float arn = bf2f(packedb[(size_t)node * 16 + 11]);

    float acc = 0.f, ds = 0.f;
    for (int i = beg + sub; i < end; i += 4) {
        int s = esrc[i];
        unsigned short raw = (li < 12) ? packedb[(size_t)s * 16 + li] : (unsigned short)0;
        float v = bf2f(raw);
        float al2s = __shfl(v, 10, 16);
        float e = __expf(lrelu(al2s + arn));
        if (li < NC2) acc += v * e;
        ds += e;
    }
    #pragma unroll
    for (int d = 16; d <= 32; d <<= 1) {
        acc += __shfl_xor(acc, d);
        ds  += __shfl_xor(ds, d);
    }
    float z = (li < NC2) ? acc / (ds + EPSF) + b2[li] : -1e30f;
    float m = z;
    #pragma unroll
    for (int d = 8; d >= 1; d >>= 1) m = fmaxf(m, __shfl_xor(m, d, 16));
    float ex = (li < NC2) ? __expf(z - m) : 0.f;
    float ss = ex;
    #pragma unroll
    for (int d = 8; d >= 1; d >>= 1) ss += __shfl_xor(ss, d, 16);
    float ls = __logf(ss) + m;
    if (lane < NC2) out[(size_t)node * NC2 + lane] = z - ls;   // group 0 writes
}

extern "C" void kernel_launch(void* const* d_in, const int* in_sizes, int n_in,
                              void* d_out, int out_size, void* d_ws, size_t ws_size,
                              hipStream_t stream)
{
    const float* x    = (const float*)d_in[0];
    const int*   ei   = (const int*)d_in[1];
    const float* W1   = (const float*)d_in[2];
    const float* as1  = (const float*)d_in[3];
    const float* ad1  = (const float*)d_in[4];
    const float* b1   = (const float*)d_in[5];
    const float* W2   = (const float*)d_in[6];
    const float* as2  = (const float*)d_in[7];
    const float* ad2  = (const float*)d_in[8];
    const float* b2   = (const float*)d_in[9];
    float* out = (float*)d_out;

    char* ws = (char*)d_ws;
    unsigned char*  h1f8 = (unsigned char*)ws;                       // NN*64 B = 6.4MB
    unsigned short* wT   = (unsigned short*)(ws + (size_t)NN * F1);  // 64KB
    unsigned short* al1b = wT + (size_t)F1 * FIN;                    // NN*8 bf16 = 1.6MB
    float* ar1 = (float*)(al1b + (size_t)NN * NH1);                  // NN*8 f32
    unsigned short* packedb = (unsigned short*)(ar1 + (size_t)NN * NH1); // NN*16 bf16 = 3.2MB
    int* cnt   = (int*)(packedb + (size_t)NN * 16);                  // NN
    int* off   = cnt + NN;                                           // NN+1
    int* bsum  = off + NN + 1;                                       // 128
    int* esrc  = bsum + 128;                                         // NTOT
    int* pos   = esrc + NTOT;                                        // NEDGE

    k_init<<<(NN + 255) / 256, 256, 0, stream>>>(W1, wT, cnt);
    k_gemm1<<<(NN + 63) / 64, 256, 0, stream>>>(x, wT, as1, ad1, h1f8, al1b, ar1);
    k_hist<<<(NEDGE + 255) / 256, 256, 0, stream>>>(ei, cnt, pos);
    k_scan1<<<NB, 256, 0, stream>>>(cnt, off, bsum);
    k_scan2<<<1, 128, 0, stream>>>(bsum, off);
    k_scan3<<<(NN + 255) / 256, 256, 0, stream>>>(off, bsum, esrc);
    k_scatter<<<(NEDGE + 255) / 256, 256, 0, stream>>>(ei, off, pos, esrc);
    k_agg1<<<NN / 4, 256, 0, stream>>>(off, esrc, al1b, ar1, h1f8, b1, W2, as2, ad2, packedb);
    k_agg2<<<NN / 4, 256, 0, stream>>>(off, esrc, packedb, b2, out);
}